// Round 14
// baseline (3545.785 us; speedup 1.0000x reference)
//
#include <hip/hip_runtime.h>
#include <hip/hip_bf16.h>

#define B_ 128
#define T_ 256
#define DV 512
#define H_ 1024
#define C_ 512

typedef _Float16 half8 __attribute__((ext_vector_type(8)));
typedef _Float16 half4 __attribute__((ext_vector_type(4)));
typedef float f32x4 __attribute__((ext_vector_type(4)));
typedef unsigned long long ull;
typedef unsigned long long ull2 __attribute__((ext_vector_type(2)));

#define SENT 0x7C007C007C007C00ULL   // 4x fp16 +inf: impossible as tanh output

__device__ __forceinline__ float sigmoidf_(float x){ return 1.f/(1.f+__expf(-x)); }
__device__ __forceinline__ float tanhf_(float x){
  x = fminf(12.f, fmaxf(-12.f, x));
  float e = __expf(2.f*x);
  return (e-1.f)/(e+1.f);
}
__device__ __forceinline__ f32x4 mfma16(half8 a, half8 b, f32x4 c){
  return __builtin_amdgcn_mfma_f32_16x16x32_f16(a, b, c, 0, 0, 0);
}
__device__ __forceinline__ bool ok8(ull v){
  return ((unsigned)v & 0xFFFFu) != 0x7C00u;
}

// ---------------- pre-kernels ----------------

__global__ void k_transpose_x(const int* __restrict__ x, int* __restrict__ xT){
  int idx = blockIdx.x*256 + threadIdx.x;
  int t = idx >> 7, b = idx & 127;
  xT[idx] = x[b*T_ + t];
}

// PT_g[tok][h] = sum_d W_g[h][d] * embed[tok][d]  -- fp16 MFMA, fp32 accum.
// grid 1536 WGs x 256 thr = 6144 waves: g=wid>>11 (3 gates x 2048 tiles),
// ht=(wid&2047)>>5 (64 h-tiles), tt=wid&31 (32 tok-tiles). Full K=512 per wave.
// Fragment layout = proven Ufrag/h-frag phi; C/D store = verified map.
__global__ __launch_bounds__(256) void k_compute_PT16(
    const float* __restrict__ embed,
    const float* __restrict__ Wz, const float* __restrict__ Wr, const float* __restrict__ Wh,
    float* __restrict__ PT){
  const int tid = threadIdx.x, lane = tid & 63, w = tid >> 6;
  const int wid = blockIdx.x*4 + w;
  const int g   = wid >> 11;
  const int rem = wid & 2047;
  const int ht  = rem >> 5;
  const int tt  = rem & 31;
  const float* Wg = (g==0)?Wz:((g==1)?Wr:Wh);

  const int hrow = ht*16 + (lane & 15);
  const int tcol = tt*16 + (lane & 15);
  const int kb   = 4*(lane >> 4);
  const float* arow = Wg    + (size_t)hrow*DV;
  const float* brow = embed + (size_t)tcol*DV;

  f32x4 acc = {0,0,0,0};
  #pragma unroll 4
  for (int kc=0; kc<16; ++kc){
    f32x4 alo = *(const f32x4*)(arow + kc*32 + kb);
    f32x4 ahi = *(const f32x4*)(arow + kc*32 + 16 + kb);
    f32x4 blo = *(const f32x4*)(brow + kc*32 + kb);
    f32x4 bhi = *(const f32x4*)(brow + kc*32 + 16 + kb);
    half8 a, b;
    #pragma unroll
    for (int e=0; e<4; ++e){
      a[e] = (_Float16)alo[e]; a[e+4] = (_Float16)ahi[e];
      b[e] = (_Float16)blo[e]; b[e+4] = (_Float16)bhi[e];
    }
    acc = mfma16(a, b, acc);
  }
  float* P = PT + (size_t)g*DV*H_;
  *(f32x4*)(P + (size_t)tcol*H_ + ht*16 + 4*(lane>>4)) = acc;
}

// U (fp32 [H][H]) -> fragment-major fp16: Ufrag[((g*64+rt)*32+kc)*64+lane][e]
__global__ __launch_bounds__(256) void k_build_Ufrag(
    const float* __restrict__ Uz, const float* __restrict__ Ur, const float* __restrict__ Uh,
    half8* __restrict__ Ufrag){
  int idx = blockIdx.x*256 + threadIdx.x;
  int l  = idx & 63;
  int kc = (idx>>6) & 31;
  int rt = (idx>>11) & 63;
  int g  = idx>>17;
  const float* Ug = (g==0)?Uz:((g==1)?Ur:Uh);
  int row = rt*16 + (l&15);
  int kb  = kc*32 + 4*(l>>4);
  f32x4 lo = *(const f32x4*)(Ug + (size_t)row*H_ + kb);
  f32x4 hi = *(const f32x4*)(Ug + (size_t)row*H_ + kb + 16);
  half8 o;
  o[0]=(_Float16)lo[0]; o[1]=(_Float16)lo[1]; o[2]=(_Float16)lo[2]; o[3]=(_Float16)lo[3];
  o[4]=(_Float16)hi[0]; o[5]=(_Float16)hi[1]; o[6]=(_Float16)hi[2]; o[7]=(_Float16)hi[3];
  Ufrag[idx] = o;
}

// fill a buffer with the fp16-inf sentinel pattern
__global__ void k_fill_sentinel(ull* __restrict__ p){
  p[blockIdx.x*256 + threadIdx.x] = SENT;
}

// ---------------- persistent recurrent kernel: full-K waves, 1 barrier/step ----------------
// grid 128 WGs x 256 thr (4 waves). WG = (c = bid&7, rb = bid>>3): rows [rb*64,+64),
// cols [c*16,+16). Wave w -> rt = rb*4+w, FULL K. No cross-wave reduction,
// ONE barrier/step, hs double-buffered. Sentinel data-poll (R10 drain-and-
// reissue) with s_sleep(4) pacing in the retry loop. Re-sentinel hoisted
// after the barrier (drains under MFMA).
__global__ __launch_bounds__(256, 1) void k_gru_persist(
    const half8* __restrict__ Ufrag,
    const float* __restrict__ PT,
    const int* __restrict__ xT,
    half8* __restrict__ hbuf0,
    half8* __restrict__ hbuf1,
    half8* __restrict__ hbuf2)
{
  __shared__ half8 hs[2][2048];       // 64 KB: double-buffered column h tile [kc][lane]

  const int tid = threadIdx.x, lane = tid & 63, w = tid >> 6;
  const int wg  = blockIdx.x;
  const int c   = wg & 7;             // column tile
  const int rb  = wg >> 3;            // row block (64 rows)
  const int rt  = rb*4 + w;           // global row tile 0..63
  const int kh  = rt >> 1;            // k-chunk holding our rows' h_old

  half8 u0[32], u1[32], u2[32];
  #pragma unroll
  for (int j=0; j<32; ++j) u0[j] = Ufrag[(((0*64+rt)*32) + j)*64 + lane];
  #pragma unroll
  for (int j=0; j<32; ++j) u1[j] = Ufrag[(((1*64+rt)*32) + j)*64 + lane];
  #pragma unroll
  for (int j=0; j<32; ++j) u2[j] = Ufrag[(((2*64+rt)*32) + j)*64 + lane];

  const int col = c*16 + (lane & 15);
  const int q = lane >> 4;
  const int rowq = rt*16 + 4*q;
  const float* PTz = PT;
  const float* PTr = PT + (size_t)DV*H_;
  const float* PTh = PT + (size_t)2*DV*H_;

  const half8* pa = hbuf0;  // h_t
  const half8* pb = hbuf1;  // h_{t+1}
  const half8* pc = hbuf2;  // h_{t+2}

  for (int t=0; t<T_; ++t){
    const int par = t & 1;

    // PT gather: independent of h; issued before the poll (latency hidden)
    int token = xT[t*B_ + col];
    f32x4 pz = *(const f32x4*)(PTz + (size_t)token*H_ + rowq);
    f32x4 pr = *(const f32x4*)(PTr + (size_t)token*H_ + rowq);
    f32x4 ph = *(const f32x4*)(PTh + (size_t)token*H_ + rowq);

    // ---- stage: sentinel data-poll of this thread's 8 chunks ----
    const ull* sbase = (const ull*)pa + (((size_t)((tid>>6)*8 + c)*64 + (tid&63)) << 1);
    ull va[16];
    unsigned miss = 0xFFu;
    #pragma unroll
    for (int s=0; s<8; ++s){
      va[2*s]   = __hip_atomic_load(sbase + s*4096,     __ATOMIC_RELAXED, __HIP_MEMORY_SCOPE_AGENT);
      va[2*s+1] = __hip_atomic_load(sbase + s*4096 + 1, __ATOMIC_RELAXED, __HIP_MEMORY_SCOPE_AGENT);
    }
    #pragma unroll
    for (int s=0; s<8; ++s)
      if (ok8(va[2*s]) && ok8(va[2*s+1])) miss &= ~(1u<<s);
    int guard = 0;
    while (miss && ++guard < (1<<12)){   // bounded: fail visibly, never hang
      __builtin_amdgcn_s_sleep(4);       // ~256 cyc: pace retries, cut IC contention
      #pragma unroll
      for (int s=0; s<8; ++s){
        if (miss & (1u<<s)){
          va[2*s]   = __hip_atomic_load(sbase + s*4096,     __ATOMIC_RELAXED, __HIP_MEMORY_SCOPE_AGENT);
          va[2*s+1] = __hip_atomic_load(sbase + s*4096 + 1, __ATOMIC_RELAXED, __HIP_MEMORY_SCOPE_AGENT);
        }
      }
      #pragma unroll
      for (int s=0; s<8; ++s){
        if ((miss & (1u<<s)) && ok8(va[2*s]) && ok8(va[2*s+1])) miss &= ~(1u<<s);
      }
    }
    #pragma unroll
    for (int s=0; s<8; ++s){
      ull2 wv; wv[0] = va[2*s]; wv[1] = va[2*s+1];
      hs[par][tid + s*256] = __builtin_bit_cast(half8, wv);
    }
    __syncthreads();   // tile staged (single barrier per step)

    // re-sentinel the h_{t+2} home slot NOW (observing full h_t transitively
    // proves all column readers of h_{t-1} finished). Drains under MFMA.
    size_t slot = (((size_t)(kh*8 + c)*64 + lane) << 1) | (unsigned)(rt & 1);
    __hip_atomic_store((ull*)pc + slot, SENT, __ATOMIC_RELAXED, __HIP_MEMORY_SCOPE_AGENT);

    // ---- MFMA phase: full K from LDS ----
    f32x4 az={0,0,0,0}, ar={0,0,0,0}, ah={0,0,0,0};
    #pragma unroll
    for (int j=0; j<32; ++j){
      half8 b = hs[par][j*64 + lane];
      az = mfma16(u0[j], b, az);
      ar = mfma16(u1[j], b, ar);
      ah = mfma16(u2[j], b, ah);
    }
    half4 hold = ((half4*)hs[par])[((kh*64 + lane) << 1) | (rt & 1)];

    // ---- epilogue (per wave, no cross-wave reduction) ----
    half4 ho;
    #pragma unroll
    for (int r=0; r<4; ++r){
      float z  = sigmoidf_(pz[r] + az[r]);
      float rr = sigmoidf_(pr[r] + ar[r]);
      float hh = tanhf_(ph[r] + rr*ah[r]);
      float hp = (float)hold[r];
      float hn = tanhf_(z*hp + (1.f-z)*hh);
      ho[r] = (_Float16)hn;
    }
    ull hval = __builtin_bit_cast(ull, ho);
    asm volatile("s_waitcnt vmcnt(0)" ::: "memory");   // prior sentinel to this buffer drained
    __hip_atomic_store((ull*)pb + slot, hval, __ATOMIC_RELAXED, __HIP_MEMORY_SCOPE_AGENT);

    const half8* tmp = pa; pa = pb; pb = pc; pc = tmp;   // rotate 3 buffers
  }
}

// ---------------- fallback per-step kernel ----------------
__global__ __launch_bounds__(256,1) void k_step(
    int t,
    const half8* __restrict__ hin,
    half8* __restrict__ hout,
    const half8* __restrict__ Ufrag,
    const float* __restrict__ PTz, const float* __restrict__ PTr, const float* __restrict__ PTh,
    const int* __restrict__ xT){
  int tid  = threadIdx.x;
  int lane = tid & 63;
  int w    = tid >> 6;
  int rp   = blockIdx.x;
  int ct   = blockIdx.y*4 + w;
  int rt0  = rp*2;

  f32x4 az0={0,0,0,0}, az1={0,0,0,0};
  f32x4 ar0={0,0,0,0}, ar1={0,0,0,0};
  f32x4 ah0={0,0,0,0}, ah1={0,0,0,0};
  half8 hold = {};

  #pragma unroll 4
  for(int kc=0; kc<32; ++kc){
    half8 b = hin[(kc*8 + ct)*64 + lane];
    half8 a;
    a = Ufrag[(((0*64 + rt0  )*32 + kc)<<6) + lane]; az0 = mfma16(a,b,az0);
    a = Ufrag[(((0*64 + rt0+1)*32 + kc)<<6) + lane]; az1 = mfma16(a,b,az1);
    a = Ufrag[(((1*64 + rt0  )*32 + kc)<<6) + lane]; ar0 = mfma16(a,b,ar0);
    a = Ufrag[(((1*64 + rt0+1)*32 + kc)<<6) + lane]; ar1 = mfma16(a,b,ar1);
    a = Ufrag[(((2*64 + rt0  )*32 + kc)<<6) + lane]; ah0 = mfma16(a,b,ah0);
    a = Ufrag[(((2*64 + rt0+1)*32 + kc)<<6) + lane]; ah1 = mfma16(a,b,ah1);
    if(kc == rp) hold = b;
  }

  int col   = ct*16 + (lane&15);
  int token = xT[t*B_ + col];
  int q     = lane>>4;
  half8 ho;
  #pragma unroll
  for(int tl=0; tl<2; ++tl){
    int rowq = rp*32 + tl*16 + 4*q;
    f32x4 pz = *(const f32x4*)(PTz + (size_t)token*H_ + rowq);
    f32x4 pr = *(const f32x4*)(PTr + (size_t)token*H_ + rowq);
    f32x4 ph = *(const f32x4*)(PTh + (size_t)token*H_ + rowq);
    f32x4 vz = tl ? az1 : az0;
    f32x4 vr = tl ? ar1 : ar0;
    f32x4 vh = tl ? ah1 : ah0;
    #pragma unroll
    for(int r=0;r<4;++r){
      float z  = sigmoidf_(pz[r] + vz[r]);
      float rr = sigmoidf_(pr[r] + vr[r]);
      float hh = tanhf_(ph[r] + rr*vh[r]);
      float hp = (float)hold[tl*4+r];
      float hn = tanhf_(z*hp + (1.f-z)*hh);
      ho[tl*4+r] = (_Float16)hn;
    }
  }
  hout[(rp*8 + ct)*64 + lane] = ho;
}

// ---------------- epilogue ----------------

__global__ void k_unfrag(const _Float16* __restrict__ hf, float* __restrict__ hlin){
  int idx = blockIdx.x*256 + threadIdx.x;  // idx = i*128 + b
  int b = idx & 127, i = idx >> 7;
  int kc = i>>5, kr = i&31;
  int l = ((kr>>2)&3)*16 + (b&15);
  int e = (kr>>4)*4 + (kr&3);
  int ct = b>>4;
  hlin[idx] = (float)hf[(((kc*8+ct)*64 + l)<<3) + e];
}

__global__ __launch_bounds__(256) void k_out_gemm(
    const float* __restrict__ hlin, const float* __restrict__ Wph,
    const float* __restrict__ bp, float* __restrict__ yT){
  __shared__ float hsm[64][128];
  int tid = threadIdx.x;
  int c0 = blockIdx.x*16;
  int cl = tid>>4, bg = tid&15;
  float acc[8] = {0,0,0,0,0,0,0,0};
  for(int i0=0;i0<H_;i0+=64){
    __syncthreads();
    for(int i=tid;i<64*128;i+=256){
      int r=i>>7, b=i&127;
      hsm[r][b] = hlin[(i0+r)*B_ + b];
    }
    __syncthreads();
    for(int il=0; il<64; ++il){
      float wv = Wph[(size_t)(c0+cl)*H_ + i0 + il];
      const float* hrow = &hsm[il][bg*8];
      #pragma unroll
      for(int j=0;j<8;++j) acc[j] += wv * hrow[j];
    }
  }
  float bias = bp[c0+cl];
  #pragma unroll
  for(int j=0;j<8;++j){
    int b = bg*8+j;
    yT[(size_t)b*C_ + c0+cl] = acc[j] + bias;
  }
}

__global__ __launch_bounds__(256) void k_logsoftmax(const float* __restrict__ yT, float* __restrict__ out){
  __shared__ float red[256];
  int b = blockIdx.x, tid = threadIdx.x;
  float v0 = yT[(size_t)b*C_ + tid];
  float v1 = yT[(size_t)b*C_ + 256 + tid];
  red[tid] = fmaxf(v0,v1); __syncthreads();
  for(int s=128;s>0;s>>=1){ if(tid<s) red[tid]=fmaxf(red[tid],red[tid+s]); __syncthreads(); }
  float M = red[0]; __syncthreads();
  red[tid] = __expf(v0-M)+__expf(v1-M); __syncthreads();
  for(int s=128;s>0;s>>=1){ if(tid<s) red[tid]+=red[tid+s]; __syncthreads(); }
  float L = M + logf(red[0]);
  out[(size_t)b*C_ + tid]       = v0 - L;
  out[(size_t)b*C_ + 256 + tid] = v1 - L;
}

// ---------------- launcher ----------------

extern "C" void kernel_launch(void* const* d_in, const int* in_sizes, int n_in,
                              void* d_out, int out_size, void* d_ws, size_t ws_size,
                              hipStream_t stream){
  const int*   x    = (const int*)  d_in[0];
  const float* embed= (const float*)d_in[1];
  const float* Wz   = (const float*)d_in[2];
  const float* Uz   = (const float*)d_in[3];
  const float* Wr   = (const float*)d_in[4];
  const float* Ur   = (const float*)d_in[5];
  const float* Wh   = (const float*)d_in[6];
  const float* Uh   = (const float*)d_in[7];
  const float* Wph  = (const float*)d_in[8];
  const float* bp   = (const float*)d_in[9];
  float* out = (float*)d_out;

  char* w = (char*)d_ws;
  float*    PT    = (float*)(w);                                // 6 MB
  half8*    Ufrag = (half8*)(w + (6u<<20));                      // 6 MB
  _Float16* hbuf0 = (_Float16*)(w + (12u<<20));                  // 256 KB
  _Float16* hbuf1 = (_Float16*)(w + (12u<<20) + (256u<<10));     // 256 KB
  _Float16* hbuf2 = (_Float16*)(w + (12u<<20) + (512u<<10));     // 256 KB
  int*      xT    = (int*)(w + (12u<<20) + (768u<<10));          // 128 KB
  float*    hlin  = (float*)(w + (12u<<20) + (896u<<10));        // 512 KB
  float*    yT    = (float*)(w + (12u<<20) + (1408u<<10));       // 256 KB

  k_transpose_x<<<128,256,0,stream>>>(x, xT);
  k_compute_PT16<<<1536,256,0,stream>>>(embed, Wz, Wr, Wh, PT);
  k_build_Ufrag<<<1536,256,0,stream>>>(Uz, Ur, Uh, Ufrag);
  (void)hipMemsetAsync(hbuf0, 0, 256u<<10, stream);             // h_0 = 0 (valid data)
  k_fill_sentinel<<<128,256,0,stream>>>((ull*)hbuf1);           // h_1 home: sentinel
  k_fill_sentinel<<<128,256,0,stream>>>((ull*)hbuf2);           // h_2 home: sentinel

  const half8* Ufrag_c = (const half8*)Ufrag;
  const float* PT_c = PT;
  const int*   xT_c = xT;
  half8* h0p = (half8*)hbuf0;
  half8* h1p = (half8*)hbuf1;
  half8* h2p = (half8*)hbuf2;
  void* args[6] = { (void*)&Ufrag_c, (void*)&PT_c, (void*)&xT_c,
                    (void*)&h0p, (void*)&h1p, (void*)&h2p };
  hipError_t ce = hipLaunchCooperativeKernel((const void*)k_gru_persist,
                                             dim3(128), dim3(256), args, 0, stream);
  if (ce != hipSuccess){
    // deterministic fallback: per-step launches, same 3-buffer rotation
    _Float16* hb[3] = {hbuf0, hbuf1, hbuf2};
    for(int t=0;t<T_;++t){
      k_step<<<dim3(32,2),256,0,stream>>>(t,
          (const half8*)hb[t%3], (half8*)hb[(t+1)%3],
          (const half8*)Ufrag,
          PT, PT + (size_t)DV*H_, PT + (size_t)2*DV*H_, xT);
    }
  }

  // h_256 lives in buf[256 % 3] = hbuf1 (both paths)
  k_unfrag<<<512,256,0,stream>>>(hbuf1, hlin);
  k_out_gemm<<<32,256,0,stream>>>(hlin, Wph, bp, yT);
  k_logsoftmax<<<128,256,0,stream>>>(yT, out);
}

// Round 15
// 3526.812 us; speedup vs baseline: 1.0054x; 1.0054x over previous
//
#include <hip/hip_runtime.h>
#include <hip/hip_bf16.h>

#define B_ 128
#define T_ 256
#define DV 512
#define H_ 1024
#define C_ 512

typedef _Float16 half8 __attribute__((ext_vector_type(8)));
typedef _Float16 half4 __attribute__((ext_vector_type(4)));
typedef float f32x4 __attribute__((ext_vector_type(4)));
typedef unsigned long long ull;
typedef unsigned long long ull2 __attribute__((ext_vector_type(2)));

#define SENT 0x7C007C007C007C00ULL   // 4x fp16 +inf: impossible as tanh output

__device__ __forceinline__ float sigmoidf_(float x){ return 1.f/(1.f+__expf(-x)); }
__device__ __forceinline__ float tanhf_(float x){
  x = fminf(12.f, fmaxf(-12.f, x));
  float e = __expf(2.f*x);
  return (e-1.f)/(e+1.f);
}
__device__ __forceinline__ f32x4 mfma16(half8 a, half8 b, f32x4 c){
  return __builtin_amdgcn_mfma_f32_16x16x32_f16(a, b, c, 0, 0, 0);
}
__device__ __forceinline__ bool ok8(ull v){
  return ((unsigned)v & 0xFFFFu) != 0x7C00u;
}

// ---------------- pre-kernels ----------------

__global__ void k_transpose_x(const int* __restrict__ x, int* __restrict__ xT){
  int idx = blockIdx.x*256 + threadIdx.x;
  int t = idx >> 7, b = idx & 127;
  xT[idx] = x[b*T_ + t];
}

// PT_g[tok][h] = sum_d W_g[h][d] * embed[tok][d]  -- fp16 MFMA, fp32 accum.
// grid 1536 WGs x 256 thr = 6144 waves: g=wid>>11 (3 gates x 2048 tiles),
// ht=(wid&2047)>>5 (64 h-tiles), tt=wid&31 (32 tok-tiles). Full K=512 per wave.
__global__ __launch_bounds__(256) void k_compute_PT16(
    const float* __restrict__ embed,
    const float* __restrict__ Wz, const float* __restrict__ Wr, const float* __restrict__ Wh,
    float* __restrict__ PT){
  const int tid = threadIdx.x, lane = tid & 63, w = tid >> 6;
  const int wid = blockIdx.x*4 + w;
  const int g   = wid >> 11;
  const int rem = wid & 2047;
  const int ht  = rem >> 5;
  const int tt  = rem & 31;
  const float* Wg = (g==0)?Wz:((g==1)?Wr:Wh);

  const int hrow = ht*16 + (lane & 15);
  const int tcol = tt*16 + (lane & 15);
  const int kb   = 4*(lane >> 4);
  const float* arow = Wg    + (size_t)hrow*DV;
  const float* brow = embed + (size_t)tcol*DV;

  f32x4 acc = {0,0,0,0};
  #pragma unroll 4
  for (int kc=0; kc<16; ++kc){
    f32x4 alo = *(const f32x4*)(arow + kc*32 + kb);
    f32x4 ahi = *(const f32x4*)(arow + kc*32 + 16 + kb);
    f32x4 blo = *(const f32x4*)(brow + kc*32 + kb);
    f32x4 bhi = *(const f32x4*)(brow + kc*32 + 16 + kb);
    half8 a, b;
    #pragma unroll
    for (int e=0; e<4; ++e){
      a[e] = (_Float16)alo[e]; a[e+4] = (_Float16)ahi[e];
      b[e] = (_Float16)blo[e]; b[e+4] = (_Float16)bhi[e];
    }
    acc = mfma16(a, b, acc);
  }
  float* P = PT + (size_t)g*DV*H_;
  *(f32x4*)(P + (size_t)tcol*H_ + ht*16 + 4*(lane>>4)) = acc;
}

// U (fp32 [H][H]) -> fragment-major fp16: Ufrag[((g*64+rt)*32+kc)*64+lane][e]
__global__ __launch_bounds__(256) void k_build_Ufrag(
    const float* __restrict__ Uz, const float* __restrict__ Ur, const float* __restrict__ Uh,
    half8* __restrict__ Ufrag){
  int idx = blockIdx.x*256 + threadIdx.x;
  int l  = idx & 63;
  int kc = (idx>>6) & 31;
  int rt = (idx>>11) & 63;
  int g  = idx>>17;
  const float* Ug = (g==0)?Uz:((g==1)?Ur:Uh);
  int row = rt*16 + (l&15);
  int kb  = kc*32 + 4*(l>>4);
  f32x4 lo = *(const f32x4*)(Ug + (size_t)row*H_ + kb);
  f32x4 hi = *(const f32x4*)(Ug + (size_t)row*H_ + kb + 16);
  half8 o;
  o[0]=(_Float16)lo[0]; o[1]=(_Float16)lo[1]; o[2]=(_Float16)lo[2]; o[3]=(_Float16)lo[3];
  o[4]=(_Float16)hi[0]; o[5]=(_Float16)hi[1]; o[6]=(_Float16)hi[2]; o[7]=(_Float16)hi[3];
  Ufrag[idx] = o;
}

// fill a buffer with the fp16-inf sentinel pattern
__global__ void k_fill_sentinel(ull* __restrict__ p){
  p[blockIdx.x*256 + threadIdx.x] = SENT;
}

// ---------------- persistent recurrent kernel: full-K waves, 1 barrier/step ----------------
// grid 128 WGs x 256 thr (4 waves). WG = (c = bid&7, rb = bid>>3): rows [rb*64,+64),
// cols [c*16,+16). Wave w -> rt = rb*4+w, FULL K. No cross-wave reduction,
// ONE barrier/step, hs double-buffered. Sentinel data-poll (drain-and-reissue)
// with s_sleep(4) pacing (measured neutral). Re-sentinel hoisted after barrier.
__global__ __launch_bounds__(256, 1) void k_gru_persist(
    const half8* __restrict__ Ufrag,
    const float* __restrict__ PT,
    const int* __restrict__ xT,
    half8* __restrict__ hbuf0,
    half8* __restrict__ hbuf1,
    half8* __restrict__ hbuf2)
{
  __shared__ half8 hs[2][2048];       // 64 KB: double-buffered column h tile [kc][lane]

  const int tid = threadIdx.x, lane = tid & 63, w = tid >> 6;
  const int wg  = blockIdx.x;
  const int c   = wg & 7;             // column tile
  const int rb  = wg >> 3;            // row block (64 rows)
  const int rt  = rb*4 + w;           // global row tile 0..63
  const int kh  = rt >> 1;            // k-chunk holding our rows' h_old

  half8 u0[32], u1[32], u2[32];
  #pragma unroll
  for (int j=0; j<32; ++j) u0[j] = Ufrag[(((0*64+rt)*32) + j)*64 + lane];
  #pragma unroll
  for (int j=0; j<32; ++j) u1[j] = Ufrag[(((1*64+rt)*32) + j)*64 + lane];
  #pragma unroll
  for (int j=0; j<32; ++j) u2[j] = Ufrag[(((2*64+rt)*32) + j)*64 + lane];

  const int col = c*16 + (lane & 15);
  const int q = lane >> 4;
  const int rowq = rt*16 + 4*q;
  const float* PTz = PT;
  const float* PTr = PT + (size_t)DV*H_;
  const float* PTh = PT + (size_t)2*DV*H_;

  const half8* pa = hbuf0;  // h_t
  const half8* pb = hbuf1;  // h_{t+1}
  const half8* pc = hbuf2;  // h_{t+2}

  for (int t=0; t<T_; ++t){
    const int par = t & 1;

    // PT gather: independent of h; issued before the poll (latency hidden)
    int token = xT[t*B_ + col];
    f32x4 pz = *(const f32x4*)(PTz + (size_t)token*H_ + rowq);
    f32x4 pr = *(const f32x4*)(PTr + (size_t)token*H_ + rowq);
    f32x4 ph = *(const f32x4*)(PTh + (size_t)token*H_ + rowq);

    // ---- stage: sentinel data-poll of this thread's 8 chunks ----
    const ull* sbase = (const ull*)pa + (((size_t)((tid>>6)*8 + c)*64 + (tid&63)) << 1);
    ull va[16];
    unsigned miss = 0xFFu;
    #pragma unroll
    for (int s=0; s<8; ++s){
      va[2*s]   = __hip_atomic_load(sbase + s*4096,     __ATOMIC_RELAXED, __HIP_MEMORY_SCOPE_AGENT);
      va[2*s+1] = __hip_atomic_load(sbase + s*4096 + 1, __ATOMIC_RELAXED, __HIP_MEMORY_SCOPE_AGENT);
    }
    #pragma unroll
    for (int s=0; s<8; ++s)
      if (ok8(va[2*s]) && ok8(va[2*s+1])) miss &= ~(1u<<s);
    int guard = 0;
    while (miss && ++guard < (1<<12)){   // bounded: fail visibly, never hang
      __builtin_amdgcn_s_sleep(4);       // pace retries (measured neutral)
      #pragma unroll
      for (int s=0; s<8; ++s){
        if (miss & (1u<<s)){
          va[2*s]   = __hip_atomic_load(sbase + s*4096,     __ATOMIC_RELAXED, __HIP_MEMORY_SCOPE_AGENT);
          va[2*s+1] = __hip_atomic_load(sbase + s*4096 + 1, __ATOMIC_RELAXED, __HIP_MEMORY_SCOPE_AGENT);
        }
      }
      #pragma unroll
      for (int s=0; s<8; ++s){
        if ((miss & (1u<<s)) && ok8(va[2*s]) && ok8(va[2*s+1])) miss &= ~(1u<<s);
      }
    }
    #pragma unroll
    for (int s=0; s<8; ++s){
      ull2 wv; wv[0] = va[2*s]; wv[1] = va[2*s+1];
      hs[par][tid + s*256] = __builtin_bit_cast(half8, wv);
    }
    __syncthreads();   // tile staged (single barrier per step)

    // re-sentinel the h_{t+2} home slot NOW (observing full h_t transitively
    // proves all column readers of h_{t-1} finished). Drains under MFMA.
    size_t slot = (((size_t)(kh*8 + c)*64 + lane) << 1) | (unsigned)(rt & 1);
    __hip_atomic_store((ull*)pc + slot, SENT, __ATOMIC_RELAXED, __HIP_MEMORY_SCOPE_AGENT);

    // ---- MFMA phase: full K from LDS ----
    f32x4 az={0,0,0,0}, ar={0,0,0,0}, ah={0,0,0,0};
    #pragma unroll
    for (int j=0; j<32; ++j){
      half8 b = hs[par][j*64 + lane];
      az = mfma16(u0[j], b, az);
      ar = mfma16(u1[j], b, ar);
      ah = mfma16(u2[j], b, ah);
    }
    half4 hold = ((half4*)hs[par])[((kh*64 + lane) << 1) | (rt & 1)];

    // ---- epilogue (per wave, no cross-wave reduction) ----
    half4 ho;
    #pragma unroll
    for (int r=0; r<4; ++r){
      float z  = sigmoidf_(pz[r] + az[r]);
      float rr = sigmoidf_(pr[r] + ar[r]);
      float hh = tanhf_(ph[r] + rr*ah[r]);
      float hp = (float)hold[r];
      float hn = tanhf_(z*hp + (1.f-z)*hh);
      ho[r] = (_Float16)hn;
    }
    ull hval = __builtin_bit_cast(ull, ho);
    asm volatile("s_waitcnt vmcnt(0)" ::: "memory");   // prior sentinel to this buffer drained
    __hip_atomic_store((ull*)pb + slot, hval, __ATOMIC_RELAXED, __HIP_MEMORY_SCOPE_AGENT);

    const half8* tmp = pa; pa = pb; pb = pc; pc = tmp;   // rotate 3 buffers
  }
}

// ---------------- fallback per-step kernel ----------------
__global__ __launch_bounds__(256,1) void k_step(
    int t,
    const half8* __restrict__ hin,
    half8* __restrict__ hout,
    const half8* __restrict__ Ufrag,
    const float* __restrict__ PTz, const float* __restrict__ PTr, const float* __restrict__ PTh,
    const int* __restrict__ xT){
  int tid  = threadIdx.x;
  int lane = tid & 63;
  int w    = tid >> 6;
  int rp   = blockIdx.x;
  int ct   = blockIdx.y*4 + w;
  int rt0  = rp*2;

  f32x4 az0={0,0,0,0}, az1={0,0,0,0};
  f32x4 ar0={0,0,0,0}, ar1={0,0,0,0};
  f32x4 ah0={0,0,0,0}, ah1={0,0,0,0};
  half8 hold = {};

  #pragma unroll 4
  for(int kc=0; kc<32; ++kc){
    half8 b = hin[(kc*8 + ct)*64 + lane];
    half8 a;
    a = Ufrag[(((0*64 + rt0  )*32 + kc)<<6) + lane]; az0 = mfma16(a,b,az0);
    a = Ufrag[(((0*64 + rt0+1)*32 + kc)<<6) + lane]; az1 = mfma16(a,b,az1);
    a = Ufrag[(((1*64 + rt0  )*32 + kc)<<6) + lane]; ar0 = mfma16(a,b,ar0);
    a = Ufrag[(((1*64 + rt0+1)*32 + kc)<<6) + lane]; ar1 = mfma16(a,b,ar1);
    a = Ufrag[(((2*64 + rt0  )*32 + kc)<<6) + lane]; ah0 = mfma16(a,b,ah0);
    a = Ufrag[(((2*64 + rt0+1)*32 + kc)<<6) + lane]; ah1 = mfma16(a,b,ah1);
    if(kc == rp) hold = b;
  }

  int col   = ct*16 + (lane&15);
  int token = xT[t*B_ + col];
  int q     = lane>>4;
  half8 ho;
  #pragma unroll
  for(int tl=0; tl<2; ++tl){
    int rowq = rp*32 + tl*16 + 4*q;
    f32x4 pz = *(const f32x4*)(PTz + (size_t)token*H_ + rowq);
    f32x4 pr = *(const f32x4*)(PTr + (size_t)token*H_ + rowq);
    f32x4 ph = *(const f32x4*)(PTh + (size_t)token*H_ + rowq);
    f32x4 vz = tl ? az1 : az0;
    f32x4 vr = tl ? ar1 : ar0;
    f32x4 vh = tl ? ah1 : ah0;
    #pragma unroll
    for(int r=0;r<4;++r){
      float z  = sigmoidf_(pz[r] + vz[r]);
      float rr = sigmoidf_(pr[r] + vr[r]);
      float hh = tanhf_(ph[r] + rr*vh[r]);
      float hp = (float)hold[tl*4+r];
      float hn = tanhf_(z*hp + (1.f-z)*hh);
      ho[tl*4+r] = (_Float16)hn;
    }
  }
  hout[(rp*8 + ct)*64 + lane] = ho;
}

// ---------------- epilogue ----------------

__global__ void k_unfrag(const _Float16* __restrict__ hf, float* __restrict__ hlin){
  int idx = blockIdx.x*256 + threadIdx.x;  // idx = i*128 + b
  int b = idx & 127, i = idx >> 7;
  int kc = i>>5, kr = i&31;
  int l = ((kr>>2)&3)*16 + (b&15);
  int e = (kr>>4)*4 + (kr&3);
  int ct = b>>4;
  hlin[idx] = (float)hf[(((kc*8+ct)*64 + l)<<3) + e];
}

__global__ __launch_bounds__(256) void k_out_gemm(
    const float* __restrict__ hlin, const float* __restrict__ Wph,
    const float* __restrict__ bp, float* __restrict__ yT){
  __shared__ float hsm[64][128];
  int tid = threadIdx.x;
  int c0 = blockIdx.x*16;
  int cl = tid>>4, bg = tid&15;
  float acc[8] = {0,0,0,0,0,0,0,0};
  for(int i0=0;i0<H_;i0+=64){
    __syncthreads();
    for(int i=tid;i<64*128;i+=256){
      int r=i>>7, b=i&127;
      hsm[r][b] = hlin[(i0+r)*B_ + b];
    }
    __syncthreads();
    for(int il=0; il<64; ++il){
      float wv = Wph[(size_t)(c0+cl)*H_ + i0 + il];
      const float* hrow = &hsm[il][bg*8];
      #pragma unroll
      for(int j=0;j<8;++j) acc[j] += wv * hrow[j];
    }
  }
  float bias = bp[c0+cl];
  #pragma unroll
  for(int j=0;j<8;++j){
    int b = bg*8+j;
    yT[(size_t)b*C_ + c0+cl] = acc[j] + bias;
  }
}

__global__ __launch_bounds__(256) void k_logsoftmax(const float* __restrict__ yT, float* __restrict__ out){
  __shared__ float red[256];
  int b = blockIdx.x, tid = threadIdx.x;
  float v0 = yT[(size_t)b*C_ + tid];
  float v1 = yT[(size_t)b*C_ + 256 + tid];
  red[tid] = fmaxf(v0,v1); __syncthreads();
  for(int s=128;s>0;s>>=1){ if(tid<s) red[tid]=fmaxf(red[tid],red[tid+s]); __syncthreads(); }
  float M = red[0]; __syncthreads();
  red[tid] = __expf(v0-M)+__expf(v1-M); __syncthreads();
  for(int s=128;s>0;s>>=1){ if(tid<s) red[tid]+=red[tid+s]; __syncthreads(); }
  float L = M + logf(red[0]);
  out[(size_t)b*C_ + tid]       = v0 - L;
  out[(size_t)b*C_ + 256 + tid] = v1 - L;
}

// ---------------- launcher ----------------

extern "C" void kernel_launch(void* const* d_in, const int* in_sizes, int n_in,
                              void* d_out, int out_size, void* d_ws, size_t ws_size,
                              hipStream_t stream){
  const int*   x    = (const int*)  d_in[0];
  const float* embed= (const float*)d_in[1];
  const float* Wz   = (const float*)d_in[2];
  const float* Uz   = (const float*)d_in[3];
  const float* Wr   = (const float*)d_in[4];
  const float* Ur   = (const float*)d_in[5];
  const float* Wh   = (const float*)d_in[6];
  const float* Uh   = (const float*)d_in[7];
  const float* Wph  = (const float*)d_in[8];
  const float* bp   = (const float*)d_in[9];
  float* out = (float*)d_out;

  char* w = (char*)d_ws;
  float*    PT    = (float*)(w);                                // 6 MB
  half8*    Ufrag = (half8*)(w + (6u<<20));                      // 6 MB
  _Float16* hbuf0 = (_Float16*)(w + (12u<<20));                  // 256 KB
  _Float16* hbuf1 = (_Float16*)(w + (12u<<20) + (256u<<10));     // 256 KB
  _Float16* hbuf2 = (_Float16*)(w + (12u<<20) + (512u<<10));     // 256 KB
  int*      xT    = (int*)(w + (12u<<20) + (768u<<10));          // 128 KB
  float*    hlin  = (float*)(w + (12u<<20) + (896u<<10));        // 512 KB
  float*    yT    = (float*)(w + (12u<<20) + (1408u<<10));       // 256 KB

  k_transpose_x<<<128,256,0,stream>>>(x, xT);
  k_compute_PT16<<<1536,256,0,stream>>>(embed, Wz, Wr, Wh, PT);
  k_build_Ufrag<<<1536,256,0,stream>>>(Uz, Ur, Uh, Ufrag);
  (void)hipMemsetAsync(hbuf0, 0, 256u<<10, stream);             // h_0 = 0 (valid data)
  k_fill_sentinel<<<128,256,0,stream>>>((ull*)hbuf1);           // h_1 home: sentinel
  k_fill_sentinel<<<128,256,0,stream>>>((ull*)hbuf2);           // h_2 home: sentinel

  const half8* Ufrag_c = (const half8*)Ufrag;
  const float* PT_c = PT;
  const int*   xT_c = xT;
  half8* h0p = (half8*)hbuf0;
  half8* h1p = (half8*)hbuf1;
  half8* h2p = (half8*)hbuf2;
  void* args[6] = { (void*)&Ufrag_c, (void*)&PT_c, (void*)&xT_c,
                    (void*)&h0p, (void*)&h1p, (void*)&h2p };
  // Clear any sticky/deferred error from prior fire-and-forget launches so ce
  // reflects ONLY the cooperative launch (R14: stale error -> fallback ALSO
  // captured -> graph ran both paths, +2.4 ms).
  (void)hipGetLastError();
  hipError_t ce = hipLaunchCooperativeKernel((const void*)k_gru_persist,
                                             dim3(128), dim3(256), args, 0, stream);
  if (ce != hipSuccess){
    // deterministic fallback: per-step launches, same 3-buffer rotation
    _Float16* hb[3] = {hbuf0, hbuf1, hbuf2};
    for(int t=0;t<T_;++t){
      k_step<<<dim3(32,2),256,0,stream>>>(t,
          (const half8*)hb[t%3], (half8*)hb[(t+1)%3],
          (const half8*)Ufrag,
          PT, PT + (size_t)DV*H_, PT + (size_t)2*DV*H_, xT);
    }
  }

  // h_256 lives in buf[256 % 3] = hbuf1 (both paths)
  k_unfrag<<<512,256,0,stream>>>(hbuf1, hlin);
  k_out_gemm<<<32,256,0,stream>>>(hlin, Wph, bp, yT);
  k_logsoftmax<<<128,256,0,stream>>>(yT, out);
}

// Round 17
// 1149.750 us; speedup vs baseline: 3.0840x; 3.0675x over previous
//
#include <hip/hip_runtime.h>
#include <hip/hip_bf16.h>

#define B_ 128
#define T_ 256
#define DV 512
#define H_ 1024
#define C_ 512

typedef _Float16 half8 __attribute__((ext_vector_type(8)));
typedef _Float16 half4 __attribute__((ext_vector_type(4)));
typedef float f32x4 __attribute__((ext_vector_type(4)));
typedef unsigned long long ull;
typedef unsigned long long ull2 __attribute__((ext_vector_type(2)));

#define SENT 0x7C007C007C007C00ULL   // 4x fp16 +inf: impossible as tanh output

__device__ __forceinline__ float sigmoidf_(float x){ return 1.f/(1.f+__expf(-x)); }
__device__ __forceinline__ float tanhf_(float x){
  x = fminf(12.f, fmaxf(-12.f, x));
  float e = __expf(2.f*x);
  return (e-1.f)/(e+1.f);
}
__device__ __forceinline__ f32x4 mfma16(half8 a, half8 b, f32x4 c){
  return __builtin_amdgcn_mfma_f32_16x16x32_f16(a, b, c, 0, 0, 0);
}
__device__ __forceinline__ bool ok8(ull v){
  return ((unsigned)v & 0xFFFFu) != 0x7C00u;
}

// ---------------- pre-kernels ----------------

__global__ void k_transpose_x(const int* __restrict__ x, int* __restrict__ xT){
  int idx = blockIdx.x*256 + threadIdx.x;
  int t = idx >> 7, b = idx & 127;
  xT[idx] = x[b*T_ + t];
}

// PT_g[tok][h] = sum_d W_g[h][d] * embed[tok][d]  -- fp16 MFMA, fp32 accum.
// grid 1536 WGs x 256 thr = 6144 waves: g=wid>>11 (3 gates x 2048 tiles),
// ht=(wid&2047)>>5 (64 h-tiles), tt=wid&31 (32 tok-tiles). Full K=512 per wave.
__global__ __launch_bounds__(256) void k_compute_PT16(
    const float* __restrict__ embed,
    const float* __restrict__ Wz, const float* __restrict__ Wr, const float* __restrict__ Wh,
    float* __restrict__ PT){
  const int tid = threadIdx.x, lane = tid & 63, w = tid >> 6;
  const int wid = blockIdx.x*4 + w;
  const int g   = wid >> 11;
  const int rem = wid & 2047;
  const int ht  = rem >> 5;
  const int tt  = rem & 31;
  const float* Wg = (g==0)?Wz:((g==1)?Wr:Wh);

  const int hrow = ht*16 + (lane & 15);
  const int tcol = tt*16 + (lane & 15);
  const int kb   = 4*(lane >> 4);
  const float* arow = Wg    + (size_t)hrow*DV;
  const float* brow = embed + (size_t)tcol*DV;

  f32x4 acc = {0,0,0,0};
  #pragma unroll 4
  for (int kc=0; kc<16; ++kc){
    f32x4 alo = *(const f32x4*)(arow + kc*32 + kb);
    f32x4 ahi = *(const f32x4*)(arow + kc*32 + 16 + kb);
    f32x4 blo = *(const f32x4*)(brow + kc*32 + kb);
    f32x4 bhi = *(const f32x4*)(brow + kc*32 + 16 + kb);
    half8 a, b;
    #pragma unroll
    for (int e=0; e<4; ++e){
      a[e] = (_Float16)alo[e]; a[e+4] = (_Float16)ahi[e];
      b[e] = (_Float16)blo[e]; b[e+4] = (_Float16)bhi[e];
    }
    acc = mfma16(a, b, acc);
  }
  float* P = PT + (size_t)g*DV*H_;
  *(f32x4*)(P + (size_t)tcol*H_ + ht*16 + 4*(lane>>4)) = acc;
}

// U (fp32 [H][H]) -> fragment-major fp16: Ufrag[((g*64+rt)*32+kc)*64+lane][e]
__global__ __launch_bounds__(256) void k_build_Ufrag(
    const float* __restrict__ Uz, const float* __restrict__ Ur, const float* __restrict__ Uh,
    half8* __restrict__ Ufrag){
  int idx = blockIdx.x*256 + threadIdx.x;
  int l  = idx & 63;
  int kc = (idx>>6) & 31;
  int rt = (idx>>11) & 63;
  int g  = idx>>17;
  const float* Ug = (g==0)?Uz:((g==1)?Ur:Uh);
  int row = rt*16 + (l&15);
  int kb  = kc*32 + 4*(l>>4);
  f32x4 lo = *(const f32x4*)(Ug + (size_t)row*H_ + kb);
  f32x4 hi = *(const f32x4*)(Ug + (size_t)row*H_ + kb + 16);
  half8 o;
  o[0]=(_Float16)lo[0]; o[1]=(_Float16)lo[1]; o[2]=(_Float16)lo[2]; o[3]=(_Float16)lo[3];
  o[4]=(_Float16)hi[0]; o[5]=(_Float16)hi[1]; o[6]=(_Float16)hi[2]; o[7]=(_Float16)hi[3];
  Ufrag[idx] = o;
}

// fill a buffer with the fp16-inf sentinel pattern
__global__ void k_fill_sentinel(ull* __restrict__ p){
  p[blockIdx.x*256 + threadIdx.x] = SENT;
}

// ---------------- persistent recurrent kernel: full-K waves, 1 barrier/step ----------------
// grid 128 WGs x 256 thr (4 waves), PLAIN launch (no cooperative API): the
// kernel uses NO grid-wide barrier -- only sentinel data-polling -- so its only
// requirement is co-residency, guaranteed by capacity: 128 WGs x (256 thr,
// 64 KB LDS, 244 VGPR -> >=1 WG/CU) on 256 CUs with an otherwise-idle device.
// Producers never wait on consumers -> staggered scheduling delays, never
// deadlocks. (R13-R16 forensics: hipLaunchCooperativeKernel flakily failed to
// enqueue in the bench process; return codes untrustworthy both directions.)
// WG = (c = bid&7, rb = bid>>3): rows [rb*64,+64), cols [c*16,+16).
// Wave w -> rt = rb*4+w, FULL K. No cross-wave reduction, ONE barrier/step,
// hs double-buffered. Sentinel data-poll (drain-and-reissue, s_sleep(4) paced).
// Re-sentinel hoisted after the barrier (drains under MFMA).
__global__ __launch_bounds__(256, 1) void k_gru_persist(
    const half8* __restrict__ Ufrag,
    const float* __restrict__ PT,
    const int* __restrict__ xT,
    half8* __restrict__ hbuf0,
    half8* __restrict__ hbuf1,
    half8* __restrict__ hbuf2)
{
  __shared__ half8 hs[2][2048];       // 64 KB: double-buffered column h tile [kc][lane]

  const int tid = threadIdx.x, lane = tid & 63, w = tid >> 6;
  const int wg  = blockIdx.x;
  const int c   = wg & 7;             // column tile
  const int rb  = wg >> 3;            // row block (64 rows)
  const int rt  = rb*4 + w;           // global row tile 0..63
  const int kh  = rt >> 1;            // k-chunk holding our rows' h_old

  half8 u0[32], u1[32], u2[32];
  #pragma unroll
  for (int j=0; j<32; ++j) u0[j] = Ufrag[(((0*64+rt)*32) + j)*64 + lane];
  #pragma unroll
  for (int j=0; j<32; ++j) u1[j] = Ufrag[(((1*64+rt)*32) + j)*64 + lane];
  #pragma unroll
  for (int j=0; j<32; ++j) u2[j] = Ufrag[(((2*64+rt)*32) + j)*64 + lane];

  const int col = c*16 + (lane & 15);
  const int q = lane >> 4;
  const int rowq = rt*16 + 4*q;
  const float* PTz = PT;
  const float* PTr = PT + (size_t)DV*H_;
  const float* PTh = PT + (size_t)2*DV*H_;

  const half8* pa = hbuf0;  // h_t
  const half8* pb = hbuf1;  // h_{t+1}
  const half8* pc = hbuf2;  // h_{t+2}

  for (int t=0; t<T_; ++t){
    const int par = t & 1;

    // PT gather: independent of h; issued before the poll (latency hidden)
    int token = xT[t*B_ + col];
    f32x4 pz = *(const f32x4*)(PTz + (size_t)token*H_ + rowq);
    f32x4 pr = *(const f32x4*)(PTr + (size_t)token*H_ + rowq);
    f32x4 ph = *(const f32x4*)(PTh + (size_t)token*H_ + rowq);

    // ---- stage: sentinel data-poll of this thread's 8 chunks ----
    const ull* sbase = (const ull*)pa + (((size_t)((tid>>6)*8 + c)*64 + (tid&63)) << 1);
    ull va[16];
    unsigned miss = 0xFFu;
    #pragma unroll
    for (int s=0; s<8; ++s){
      va[2*s]   = __hip_atomic_load(sbase + s*4096,     __ATOMIC_RELAXED, __HIP_MEMORY_SCOPE_AGENT);
      va[2*s+1] = __hip_atomic_load(sbase + s*4096 + 1, __ATOMIC_RELAXED, __HIP_MEMORY_SCOPE_AGENT);
    }
    #pragma unroll
    for (int s=0; s<8; ++s)
      if (ok8(va[2*s]) && ok8(va[2*s+1])) miss &= ~(1u<<s);
    int guard = 0;
    while (miss && ++guard < (1<<13)){   // bounded: fail visibly, never hang
      __builtin_amdgcn_s_sleep(4);       // pace retries (measured neutral)
      #pragma unroll
      for (int s=0; s<8; ++s){
        if (miss & (1u<<s)){
          va[2*s]   = __hip_atomic_load(sbase + s*4096,     __ATOMIC_RELAXED, __HIP_MEMORY_SCOPE_AGENT);
          va[2*s+1] = __hip_atomic_load(sbase + s*4096 + 1, __ATOMIC_RELAXED, __HIP_MEMORY_SCOPE_AGENT);
        }
      }
      #pragma unroll
      for (int s=0; s<8; ++s){
        if ((miss & (1u<<s)) && ok8(va[2*s]) && ok8(va[2*s+1])) miss &= ~(1u<<s);
      }
    }
    #pragma unroll
    for (int s=0; s<8; ++s){
      ull2 wv; wv[0] = va[2*s]; wv[1] = va[2*s+1];
      hs[par][tid + s*256] = __builtin_bit_cast(half8, wv);
    }
    __syncthreads();   // tile staged (single barrier per step)

    // re-sentinel the h_{t+2} home slot NOW (observing full h_t transitively
    // proves all column readers of h_{t-1} finished). Drains under MFMA.
    size_t slot = (((size_t)(kh*8 + c)*64 + lane) << 1) | (unsigned)(rt & 1);
    __hip_atomic_store((ull*)pc + slot, SENT, __ATOMIC_RELAXED, __HIP_MEMORY_SCOPE_AGENT);

    // ---- MFMA phase: full K from LDS ----
    f32x4 az={0,0,0,0}, ar={0,0,0,0}, ah={0,0,0,0};
    #pragma unroll
    for (int j=0; j<32; ++j){
      half8 b = hs[par][j*64 + lane];
      az = mfma16(u0[j], b, az);
      ar = mfma16(u1[j], b, ar);
      ah = mfma16(u2[j], b, ah);
    }
    half4 hold = ((half4*)hs[par])[((kh*64 + lane) << 1) | (rt & 1)];

    // ---- epilogue (per wave, no cross-wave reduction) ----
    half4 ho;
    #pragma unroll
    for (int r=0; r<4; ++r){
      float z  = sigmoidf_(pz[r] + az[r]);
      float rr = sigmoidf_(pr[r] + ar[r]);
      float hh = tanhf_(ph[r] + rr*ah[r]);
      float hp = (float)hold[r];
      float hn = tanhf_(z*hp + (1.f-z)*hh);
      ho[r] = (_Float16)hn;
    }
    ull hval = __builtin_bit_cast(ull, ho);
    asm volatile("s_waitcnt vmcnt(0)" ::: "memory");   // prior sentinel to this buffer drained
    __hip_atomic_store((ull*)pb + slot, hval, __ATOMIC_RELAXED, __HIP_MEMORY_SCOPE_AGENT);

    const half8* tmp = pa; pa = pb; pb = pc; pc = tmp;   // rotate 3 buffers
  }
}

// ---------------- epilogue ----------------

__global__ void k_unfrag(const _Float16* __restrict__ hf, float* __restrict__ hlin){
  int idx = blockIdx.x*256 + threadIdx.x;  // idx = i*128 + b
  int b = idx & 127, i = idx >> 7;
  int kc = i>>5, kr = i&31;
  int l = ((kr>>2)&3)*16 + (b&15);
  int e = (kr>>4)*4 + (kr&3);
  int ct = b>>4;
  hlin[idx] = (float)hf[(((kc*8+ct)*64 + l)<<3) + e];
}

__global__ __launch_bounds__(256) void k_out_gemm(
    const float* __restrict__ hlin, const float* __restrict__ Wph,
    const float* __restrict__ bp, float* __restrict__ yT){
  __shared__ float hsm[64][128];
  int tid = threadIdx.x;
  int c0 = blockIdx.x*16;
  int cl = tid>>4, bg = tid&15;
  float acc[8] = {0,0,0,0,0,0,0,0};
  for(int i0=0;i0<H_;i0+=64){
    __syncthreads();
    for(int i=tid;i<64*128;i+=256){
      int r=i>>7, b=i&127;
      hsm[r][b] = hlin[(i0+r)*B_ + b];
    }
    __syncthreads();
    for(int il=0; il<64; ++il){
      float wv = Wph[(size_t)(c0+cl)*H_ + i0 + il];
      const float* hrow = &hsm[il][bg*8];
      #pragma unroll
      for(int j=0;j<8;++j) acc[j] += wv * hrow[j];
    }
  }
  float bias = bp[c0+cl];
  #pragma unroll
  for(int j=0;j<8;++j){
    int b = bg*8+j;
    yT[(size_t)b*C_ + c0+cl] = acc[j] + bias;
  }
}

__global__ __launch_bounds__(256) void k_logsoftmax(const float* __restrict__ yT, float* __restrict__ out){
  __shared__ float red[256];
  int b = blockIdx.x, tid = threadIdx.x;
  float v0 = yT[(size_t)b*C_ + tid];
  float v1 = yT[(size_t)b*C_ + 256 + tid];
  red[tid] = fmaxf(v0,v1); __syncthreads();
  for(int s=128;s>0;s>>=1){ if(tid<s) red[tid]=fmaxf(red[tid],red[tid+s]); __syncthreads(); }
  float M = red[0]; __syncthreads();
  red[tid] = __expf(v0-M)+__expf(v1-M); __syncthreads();
  for(int s=128;s>0;s>>=1){ if(tid<s) red[tid]+=red[tid+s]; __syncthreads(); }
  float L = M + logf(red[0]);
  out[(size_t)b*C_ + tid]       = v0 - L;
  out[(size_t)b*C_ + 256 + tid] = v1 - L;
}

// ---------------- launcher ----------------

extern "C" void kernel_launch(void* const* d_in, const int* in_sizes, int n_in,
                              void* d_out, int out_size, void* d_ws, size_t ws_size,
                              hipStream_t stream){
  const int*   x    = (const int*)  d_in[0];
  const float* embed= (const float*)d_in[1];
  const float* Wz   = (const float*)d_in[2];
  const float* Uz   = (const float*)d_in[3];
  const float* Wr   = (const float*)d_in[4];
  const float* Ur   = (const float*)d_in[5];
  const float* Wh   = (const float*)d_in[6];
  const float* Uh   = (const float*)d_in[7];
  const float* Wph  = (const float*)d_in[8];
  const float* bp   = (const float*)d_in[9];
  float* out = (float*)d_out;

  char* w = (char*)d_ws;
  float*    PT    = (float*)(w);                                // 6 MB
  half8*    Ufrag = (half8*)(w + (6u<<20));                      // 6 MB
  _Float16* hbuf0 = (_Float16*)(w + (12u<<20));                  // 256 KB
  _Float16* hbuf1 = (_Float16*)(w + (12u<<20) + (256u<<10));     // 256 KB
  _Float16* hbuf2 = (_Float16*)(w + (12u<<20) + (512u<<10));     // 256 KB
  int*      xT    = (int*)(w + (12u<<20) + (768u<<10));          // 128 KB
  float*    hlin  = (float*)(w + (12u<<20) + (896u<<10));        // 512 KB
  float*    yT    = (float*)(w + (12u<<20) + (1408u<<10));       // 256 KB

  k_transpose_x<<<128,256,0,stream>>>(x, xT);
  k_compute_PT16<<<1536,256,0,stream>>>(embed, Wz, Wr, Wh, PT);
  k_build_Ufrag<<<1536,256,0,stream>>>(Uz, Ur, Uh, Ufrag);
  (void)hipMemsetAsync(hbuf0, 0, 256u<<10, stream);             // h_0 = 0 (valid data)
  k_fill_sentinel<<<128,256,0,stream>>>((ull*)hbuf1);           // h_1 home: sentinel
  k_fill_sentinel<<<128,256,0,stream>>>((ull*)hbuf2);           // h_2 home: sentinel

  // PLAIN launch: kernel has no grid barrier; co-residency by capacity
  // (128 WGs, >=1 WG/CU, 256 CUs, idle device). See kernel comment.
  k_gru_persist<<<dim3(128), dim3(256), 0, stream>>>(
      (const half8*)Ufrag, PT, xT,
      (half8*)hbuf0, (half8*)hbuf1, (half8*)hbuf2);

  // h_256 lives in hbuf1 (3-buffer rotation: 256 % 3 = 1)
  k_unfrag<<<512,256,0,stream>>>(hbuf1, hlin);
  k_out_gemm<<<32,256,0,stream>>>(hlin, Wph, bp, yT);
  k_logsoftmax<<<128,256,0,stream>>>(yT, out);
}